// Round 1
// baseline (393.492 us; speedup 1.0000x reference)
//
#include <hip/hip_runtime.h>
#include <hip/hip_bf16.h>

// O[b,i,h,p] = sum_{c=l*3+j in 768, tap in 3} W[l,j,tap,i] * S_{b,h}[c][p+tap]
// S[c][t]: t=0,8,9 -> 0; t=(w+1)%7+1 <- V[c][w]
// V[c][w] = x[b,l,r1,w]*[0<=r1<7] + x[b,256+l,r2,w]*[0<=r2<7],
//   r1 = h+j-1, r2 = ((h+6)%7)+j-1            (verified rounds 1-2)
//
// Round 3: V precomputed into d_ws as Vt[bh][r=(w+1)%7][c] bf16 (77 MB).
// Round 4: prep_v rewritten — old version was transaction-bound (98 scalar
// 4B global loads/thread at 196B lane stride + 147 scalar 2B stores at 6B
// lane stride, ~185 us). New version: LDS-stage x[b, half] with coalesced
// float4 loads, compute V from LDS, emit coalesced bf16x8 stores.

typedef __bf16 bf16x8 __attribute__((ext_vector_type(8)));
typedef float f32x4 __attribute__((ext_vector_type(4)));

#define VT_OFFSET (4u << 20)                       // W2 at d_ws+0, Vt at d_ws+4MB
#define VT_BYTES  (7168ull * 7 * 768 * 2)          // 77,070,336
#define WS_NEED   (VT_OFFSET + VT_BYTES)

__global__ __launch_bounds__(256) void prep_w(const float* __restrict__ Wg,
                                              __bf16* __restrict__ W2) {
    int idx = blockIdx.x * 256 + threadIdx.x;      // over 512*2304
    int i = idx / 2304;
    int kk = idx - i * 2304;
    int tap = kk / 768;
    int c = kk - tap * 768;
    W2[idx] = (__bf16)Wg[(c * 3 + tap) * 512 + i];
}

// Block per (b, g) with g = channel-half (l = g*128 .. g*128+127).
// Stage x[b, g*128..+127] (group a) and x[b, 256+g*128..+127] (group b)
// into LDS coalesced; compute V; write Vt rows coalesced as bf16x8.
__global__ __launch_bounds__(256) void prep_v(const float* __restrict__ x,
                                              __bf16* __restrict__ Vt) {
    __shared__ float xs[256 * 49];                 // 50,176 B: rows 0..127 = grp a,
                                                   // rows 128..255 = grp b
    const int b = blockIdx.x >> 1;
    const int g = blockIdx.x & 1;
    const int tid = threadIdx.x;

    {
        // 128 rows * 49 floats = 6272 floats = 1568 float4 per half, contiguous
        const float4* src0 = (const float4*)(x + ((size_t)b * 512 + g * 128) * 49);
        const float4* src1 = (const float4*)(x + ((size_t)b * 512 + 256 + g * 128) * 49);
        float4* dst0 = (float4*)xs;
        float4* dst1 = (float4*)(xs + 128 * 49);
        #pragma unroll
        for (int it = 0; it < 7; ++it) {
            const int q = it * 256 + tid;
            if (q < 1568) dst0[q] = src0[q];
        }
        #pragma unroll
        for (int it = 0; it < 7; ++it) {
            const int q = it * 256 + tid;
            if (q < 1568) dst1[q] = src1[q];
        }
    }
    __syncthreads();

    // Per h: 7 r-rows x 384 c (this half) = 336 bf16x8 stores, 2 iters/thread.
    for (int h = 0; h < 7; ++h) {
        const int hm = (h + 6) % 7;
        for (int it = 0; it < 2; ++it) {
            const int u = it * 256 + tid;
            if (u < 336) {
                const int r = u / 48;              // 0..6  (Vt row within h)
                const int k = u - r * 48;          // 0..47 (16B unit within row-half)
                const int w = (r + 6) % 7;         // r = (w+1)%7  <=>  w = (r+6)%7
                bf16x8 vv;
                #pragma unroll
                for (int e = 0; e < 8; ++e) {
                    const int c = k * 8 + e;       // local c in 0..383
                    const int l = c / 3;           // local l in 0..127
                    const int j = c - 3 * l;
                    const int r1 = h + j - 1;
                    const int r2 = hm + j - 1;
                    float v = 0.f;
                    if (r1 >= 0 && r1 < 7) v += xs[l * 49 + r1 * 7 + w];
                    if (r2 >= 0 && r2 < 7) v += xs[(128 + l) * 49 + r2 * 7 + w];
                    vv[e] = (__bf16)v;
                }
                *(bf16x8*)(Vt + (size_t)((b * 7 + h) * 7 + r) * 768 + g * 384 + k * 8) = vv;
            }
        }
    }
}

__global__ __launch_bounds__(256) void gemm_vt(const __bf16* __restrict__ Vt,
                                               const __bf16* __restrict__ W2,
                                               float* __restrict__ out) {
    __shared__ __bf16 T[16 * 400];       // [bh16][t10][c32], t-stride 40 bf16
    __shared__ __bf16 Bt[128 * 104];     // [n128][tap*32+c], row stride 104 bf16

    const int tid = threadIdx.x;
    // XCD swizzle: the 4 N-siblings of one mb are g, g+8, g+16, g+24 -> same XCD
    const int g0 = blockIdx.x;
    const int nb = (g0 >> 3) & 3;
    const int mb = ((g0 >> 5) << 3) | (g0 & 7);
    const int i0 = nb * 128;

    // zero T once (rows t=0,8,9 stay zero; rows 1..7 are re-staged per chunk)
    for (int q = tid; q < 3200; q += 256) ((int*)T)[q] = 0;

    const int lane = tid & 63;
    const int wave = tid >> 6;
    const int wm = wave >> 1;            // 2x2 wave grid, each 64x64
    const int wn = wave & 1;
    const int ln15 = lane & 15;
    const int gq = lane >> 4;

    f32x4 acc[4][4];
    #pragma unroll
    for (int a = 0; a < 4; ++a)
        #pragma unroll
        for (int bq = 0; bq < 4; ++bq) acc[a][bq] = (f32x4){0.f, 0.f, 0.f, 0.f};

    __syncthreads();                     // T zeroing complete before staging

    for (int chunk = 0; chunk < 24; ++chunk) {
        // ---- stage T: 448 16B units (16 bh x 7 t x 4 q), 2 iters ----
        #pragma unroll
        for (int it = 0; it < 2; ++it) {
            const int u = it * 256 + tid;
            if (u < 448) {
                const int q = u & 3;
                const int tmp = u >> 2;          // 0..111
                const int t = tmp % 7;
                const int bh = tmp / 7;
                const float4 val = *(const float4*)(
                    Vt + (size_t)((mb * 16 + bh) * 7 + t) * 768 + chunk * 32 + q * 8);
                *(float4*)(&T[bh * 400 + (t + 1) * 40 + q * 8]) = val;
            }
        }
        // ---- stage Bt: 1536 16B units, 6 per thread ----
        #pragma unroll
        for (int it = 0; it < 6; ++it) {
            const int u = it * 256 + tid;        // u = tap*512 + n*4 + q
            const int tap = u >> 9;
            const int rem = u & 511;
            const int n = rem >> 2;
            const int q = rem & 3;
            const float4 val = *(const float4*)(W2 + (size_t)(i0 + n) * 2304 +
                                                tap * 768 + chunk * 32 + q * 8);
            *(float4*)(&Bt[n * 104 + tap * 32 + q * 8]) = val;
        }

        __syncthreads();

        // ---- MFMA: 3 taps x (4 Mfrag x 4 Nfrag) per wave ----
        #pragma unroll
        for (int tap = 0; tap < 3; ++tap) {
            bf16x8 af[4], bfr[4];
            #pragma unroll
            for (int mf = 0; mf < 4; ++mf) {
                const int bh_l = wm * 8 + mf * 2 + (ln15 >> 3);
                const int p = ln15 & 7;
                af[mf] = *(const bf16x8*)(&T[(bh_l * 10 + p + tap) * 40 + gq * 8]);
            }
            #pragma unroll
            for (int nf = 0; nf < 4; ++nf) {
                const int n_l = wn * 64 + nf * 16 + ln15;
                bfr[nf] = *(const bf16x8*)(&Bt[n_l * 104 + tap * 32 + gq * 8]);
            }
            #pragma unroll
            for (int mf = 0; mf < 4; ++mf)
                #pragma unroll
                for (int nf = 0; nf < 4; ++nf)
                    acc[mf][nf] = __builtin_amdgcn_mfma_f32_16x16x32_bf16(
                        af[mf], bfr[nf], acc[mf][nf], 0, 0, 0);
        }

        __syncthreads();
    }

    // ---- epilogue: D row = quad*4+reg, col = lane&15 ----
    #pragma unroll
    for (int mf = 0; mf < 4; ++mf) {
        #pragma unroll
        for (int r = 0; r < 4; ++r) {
            const int mrow = gq * 4 + r;                 // 0..15
            const int Mg_l = wm * 64 + mf * 16 + mrow;
            const int p = Mg_l & 7;
            if (p == 7) continue;                        // padded row
            const int bh_l = Mg_l >> 3;
            const int bhg = mb * 16 + bh_l;
            const int b = bhg / 7;
            const int h = bhg - 7 * b;
            #pragma unroll
            for (int nf = 0; nf < 4; ++nf) {
                const int i = i0 + wn * 64 + nf * 16 + ln15;
                out[(((size_t)b * 512 + i) * 7 + h) * 7 + p] = acc[mf][nf][r];
            }
        }
    }
}

// ---------------- fallback (round-2 implicit staging) if ws is small --------
__global__ __launch_bounds__(256) void gemm_shift(const float* __restrict__ x,
                                                  const __bf16* __restrict__ W2,
                                                  float* __restrict__ out) {
    __shared__ __bf16 T[16 * 10 * 40];
    __shared__ __bf16 Bt[128 * 104];

    const int tid = threadIdx.x;
    const int mb = blockIdx.x >> 2;
    const int nb = blockIdx.x & 3;
    const int i0 = nb * 128;

    const int cl  = tid & 31;
    const int bh0 = tid >> 5;
    const int bhg0 = mb * 16 + bh0;
    const int bhg1 = bhg0 + 8;
    const int b0 = bhg0 / 7, h0 = bhg0 - 7 * b0;
    const int b1 = bhg1 / 7, h1 = bhg1 - 7 * b1;
    const int hm0 = (h0 + 6) % 7, hm1 = (h1 + 6) % 7;

    for (int q = tid; q < 16 * 10 * 40 / 2; q += 256) ((int*)T)[q] = 0;

    const int lane = tid & 63;
    const int wave = tid >> 6;
    const int wm = wave >> 1;
    const int wn = wave & 1;
    const int ln15 = lane & 15;
    const int gq = lane >> 4;

    f32x4 acc[4][4];
    #pragma unroll
    for (int a = 0; a < 4; ++a)
        #pragma unroll
        for (int bq = 0; bq < 4; ++bq) acc[a][bq] = (f32x4){0.f, 0.f, 0.f, 0.f};

    __syncthreads();

    for (int chunk = 0; chunk < 24; ++chunk) {
        const int cg = chunk * 32 + cl;
        const int l = cg / 3;
        const int j = cg - 3 * l;
        {
            const int r1 = h0 + j - 1, r2 = hm0 + j - 1;
            float v[7] = {0.f, 0.f, 0.f, 0.f, 0.f, 0.f, 0.f};
            if (r1 >= 0 && r1 < 7) {
                const float* p1 = x + (((size_t)b0 * 512 + l) * 7 + r1) * 7;
                #pragma unroll
                for (int w = 0; w < 7; ++w) v[w] += p1[w];
            }
            if (r2 >= 0 && r2 < 7) {
                const float* p2 = x + (((size_t)b0 * 512 + 256 + l) * 7 + r2) * 7;
                #pragma unroll
                for (int w = 0; w < 7; ++w) v[w] += p2[w];
            }
            #pragma unroll
            for (int w = 0; w < 7; ++w)
                T[bh0 * 400 + ((w + 1) % 7 + 1) * 40 + cl] = (__bf16)v[w];
        }
        {
            const int r1 = h1 + j - 1, r2 = hm1 + j - 1;
            float v[7] = {0.f, 0.f, 0.f, 0.f, 0.f, 0.f, 0.f};
            if (r1 >= 0 && r1 < 7) {
                const float* p1 = x + (((size_t)b1 * 512 + l) * 7 + r1) * 7;
                #pragma unroll
                for (int w = 0; w < 7; ++w) v[w] += p1[w];
            }
            if (r2 >= 0 && r2 < 7) {
                const float* p2 = x + (((size_t)b1 * 512 + 256 + l) * 7 + r2) * 7;
                #pragma unroll
                for (int w = 0; w < 7; ++w) v[w] += p2[w];
            }
            #pragma unroll
            for (int w = 0; w < 7; ++w)
                T[(bh0 + 8) * 400 + ((w + 1) % 7 + 1) * 40 + cl] = (__bf16)v[w];
        }

        #pragma unroll
        for (int it = 0; it < 6; ++it) {
            const int u = it * 256 + tid;
            const int tap = u >> 9;
            const int rem = u & 511;
            const int n = rem >> 2;
            const int q = rem & 3;
            const float4 val = *(const float4*)(W2 + (size_t)(i0 + n) * 2304 +
                                                tap * 768 + chunk * 32 + q * 8);
            *(float4*)(&Bt[n * 104 + tap * 32 + q * 8]) = val;
        }

        __syncthreads();

        #pragma unroll
        for (int tap = 0; tap < 3; ++tap) {
            bf16x8 af[4], bfr[4];
            #pragma unroll
            for (int mf = 0; mf < 4; ++mf) {
                const int bh_l = wm * 8 + mf * 2 + (ln15 >> 3);
                const int p = ln15 & 7;
                af[mf] = *(const bf16x8*)(&T[(bh_l * 10 + p + tap) * 40 + gq * 8]);
            }
            #pragma unroll
            for (int nf = 0; nf < 4; ++nf) {
                const int n_l = wn * 64 + nf * 16 + ln15;
                bfr[nf] = *(const bf16x8*)(&Bt[n_l * 104 + tap * 32 + gq * 8]);
            }
            #pragma unroll
            for (int mf = 0; mf < 4; ++mf)
                #pragma unroll
                for (int nf = 0; nf < 4; ++nf)
                    acc[mf][nf] = __builtin_amdgcn_mfma_f32_16x16x32_bf16(
                        af[mf], bfr[nf], acc[mf][nf], 0, 0, 0);
        }

        __syncthreads();
    }

    #pragma unroll
    for (int mf = 0; mf < 4; ++mf) {
        #pragma unroll
        for (int r = 0; r < 4; ++r) {
            const int mrow = gq * 4 + r;
            const int Mg_l = wm * 64 + mf * 16 + mrow;
            const int p = Mg_l & 7;
            if (p == 7) continue;
            const int bh_l = Mg_l >> 3;
            const int bhg = mb * 16 + bh_l;
            const int b = bhg / 7;
            const int h = bhg - 7 * b;
            #pragma unroll
            for (int nf = 0; nf < 4; ++nf) {
                const int i = i0 + wn * 64 + nf * 16 + ln15;
                out[(((size_t)b * 512 + i) * 7 + h) * 7 + p] = acc[mf][nf][r];
            }
        }
    }
}

extern "C" void kernel_launch(void* const* d_in, const int* in_sizes, int n_in,
                              void* d_out, int out_size, void* d_ws, size_t ws_size,
                              hipStream_t stream) {
    const float* x  = (const float*)d_in[0];   // (1024,512,7,7) fp32
    const float* Wg = (const float*)d_in[1];   // (256,3,3,512) fp32
    float* out = (float*)d_out;                // (1024,512,7,7) fp32
    __bf16* W2 = (__bf16*)d_ws;                // 512*2304 bf16 = 2.36 MB

    prep_w<<<dim3(512 * 2304 / 256), dim3(256), 0, stream>>>(Wg, W2);

    if (ws_size >= WS_NEED) {
        __bf16* Vt = (__bf16*)((char*)d_ws + VT_OFFSET);
        prep_v<<<dim3(2048), dim3(256), 0, stream>>>(x, Vt);
        gemm_vt<<<dim3(448 * 4), dim3(256), 0, stream>>>(Vt, W2, out);
    } else {
        gemm_shift<<<dim3(448 * 4), dim3(256), 0, stream>>>(x, W2, out);
    }
}